// Round 2
// baseline (73.611 us; speedup 1.0000x reference)
//
#include <hip/hip_runtime.h>
#include <hip/hip_cooperative_groups.h>
#include <math.h>

namespace cg = cooperative_groups;

#define SEQ 512
#define DM  512
#define DK  64
#define NH  8
#define SCALE 0.125f   // 1/sqrt(64)
#define NB   256       // blocks  (2 rows per block)
#define NT   512       // threads (8 waves)

// ---------------------------------------------------------------------------
// Fused: phase1 QKV projection (+ reduced W_O), grid sync, phase2 attention.
// Block b owns rows 2b, 2b+1 in both phases.
// ---------------------------------------------------------------------------
__global__ __launch_bounds__(NT) void mha_fused(
    const float* __restrict__ xq, const float* __restrict__ xk,
    const float* __restrict__ amask,
    const float* __restrict__ WQ, const float* __restrict__ WK,
    const float* __restrict__ WV, const float* __restrict__ WO,
    float* __restrict__ Q, float* __restrict__ K, float* __restrict__ V,
    float* __restrict__ Wor, float* __restrict__ out)
{
    const int b   = blockIdx.x;
    const int tid = threadIdx.x;

    __shared__ float x_s[2][2][DM];          // [xq/xk][row][d]   8 KB
    __shared__ float part_s[3][8][2][DK];    // [QKV][part][row][k] 12 KB
    __shared__ __align__(16) float q_s[2][DK];
    __shared__ float p_s[2][SEQ];            // 4 KB
    __shared__ float red_s[2][4];
    __shared__ float hpart_s[2][4][DK];      // 2 KB
    __shared__ float head_s[2][DK];

    // ================= Phase 1: Q/K/V rows 2b,2b+1 (+ Wor slice) ==========
    {
        const int r0 = 2 * b;
        for (int i = tid; i < 2 * DM; i += NT) {       // coalesced row stage
            const int r = i >> 9, d = i & (DM - 1);
            x_s[0][r][d] = xq[(r0 + r) * DM + d];
            x_s[1][r][d] = xk[(r0 + r) * DM + d];
        }
        __syncthreads();

        const int k    = tid & 63;
        const int part = tid >> 6;              // 0..7 -> 64 d each
        const int d0   = part * (DM / 8);
        float aq0 = 0, aq1 = 0, ak0 = 0, ak1 = 0, av0 = 0, av1 = 0;
        #pragma unroll 8
        for (int d = d0; d < d0 + DM / 8; ++d) {
            const float wq = WQ[d * DK + k];    // wave: 64 consecutive floats
            const float wk = WK[d * DK + k];
            const float wv = WV[d * DK + k];
            aq0 += x_s[0][0][d] * wq;  aq1 += x_s[0][1][d] * wq;
            ak0 += x_s[1][0][d] * wk;  ak1 += x_s[1][1][d] * wk;
            av0 += x_s[1][0][d] * wv;  av1 += x_s[1][1][d] * wv;
        }
        part_s[0][part][0][k] = aq0;  part_s[0][part][1][k] = aq1;
        part_s[1][part][0][k] = ak0;  part_s[1][part][1][k] = ak1;
        part_s[2][part][0][k] = av0;  part_s[2][part][1][k] = av1;
        __syncthreads();

        if (tid < 3 * 2 * DK) {                 // 384 threads: reduce parts
            const int m   = tid >> 7;           // 0:Q 1:K 2:V
            const int rem = tid & 127;
            const int r   = rem >> 6;
            const int kk  = rem & 63;
            float s = 0.f;
            #pragma unroll
            for (int p = 0; p < 8; ++p) s += part_s[m][p][r][kk];
            float* dst = (m == 0) ? Q : (m == 1) ? K : V;
            dst[(r0 + r) * DK + kk] = s;
        } else {                                // 128 threads: Wor slice
            const int e = b * 128 + (tid - 384);   // flat v*512+d
            const int v = e >> 9, d = e & 511;
            float acc = 0.f;
            #pragma unroll
            for (int h = 0; h < NH; ++h) acc += WO[(h * DK + v) * DM + d];
            Wor[e] = acc;
        }
    }

    cg::this_grid().sync();

    // ================= Phase 2: attention rows 2b,2b+1 =====================
    {
        const int sub  = tid >> 8;              // half-block -> row
        const int t2   = tid & 255;
        const int lane = tid & 63;
        const int wloc = (tid >> 6) & 3;
        const int row  = 2 * b + sub;

        if (t2 < DK) q_s[sub][t2] = Q[row * DK + t2];
        __syncthreads();

        float sc[2];
        const float4* q4 = reinterpret_cast<const float4*>(q_s[sub]);
        #pragma unroll
        for (int i = 0; i < 2; ++i) {
            const int t = t2 + i * 256;
            const float4* k4 = reinterpret_cast<const float4*>(K + t * DK);
            float acc = 0.f;
            #pragma unroll
            for (int d = 0; d < DK / 4; ++d) {
                const float4 kv = k4[d], qv = q4[d];
                acc += qv.x * kv.x + qv.y * kv.y + qv.z * kv.z + qv.w * kv.w;
            }
            acc *= SCALE;
            if (amask[t] == 0.f) acc = -INFINITY;
            sc[i] = acc;
        }

        float wm = fmaxf(sc[0], sc[1]);
        #pragma unroll
        for (int off = 32; off; off >>= 1) wm = fmaxf(wm, __shfl_xor(wm, off, 64));
        if (lane == 0) red_s[sub][wloc] = wm;
        __syncthreads();
        const float bmax = fmaxf(fmaxf(red_s[sub][0], red_s[sub][1]),
                                 fmaxf(red_s[sub][2], red_s[sub][3]));
        __syncthreads();

        const float p0 = __expf(sc[0] - bmax);
        const float p1 = __expf(sc[1] - bmax);
        p_s[sub][t2]       = p0;
        p_s[sub][t2 + 256] = p1;
        float wsum = p0 + p1;
        #pragma unroll
        for (int off = 32; off; off >>= 1) wsum += __shfl_xor(wsum, off, 64);
        if (lane == 0) red_s[sub][wloc] = wsum;
        __syncthreads();
        const float inv = 1.f / (red_s[sub][0] + red_s[sub][1]
                               + red_s[sub][2] + red_s[sub][3]);

        const int t0 = wloc * (SEQ / 4);
        float hacc = 0.f;
        for (int t = t0; t < t0 + SEQ / 4; ++t)
            hacc += p_s[sub][t] * V[t * DK + lane];   // 64 consecutive floats
        hpart_s[sub][wloc][lane] = hacc;
        __syncthreads();
        if (t2 < DK)
            head_s[sub][t2] = (hpart_s[sub][0][t2] + hpart_s[sub][1][t2]
                             + hpart_s[sub][2][t2] + hpart_s[sub][3][t2]) * inv;
        __syncthreads();

        #pragma unroll
        for (int i = 0; i < 2; ++i) {
            const int d = t2 + i * 256;
            float acc = 0.f;
            #pragma unroll 8
            for (int vv = 0; vv < DK; ++vv)
                acc += head_s[sub][vv] * Wor[vv * DM + d];
            out[row * DM + d] = acc;
        }
    }
}

extern "C" void kernel_launch(void* const* d_in, const int* in_sizes, int n_in,
                              void* d_out, int out_size, void* d_ws, size_t ws_size,
                              hipStream_t stream) {
    const float* xq    = (const float*)d_in[0];
    const float* xk    = (const float*)d_in[1];
    const float* amask = (const float*)d_in[2];
    const float* WQ    = (const float*)d_in[3];
    const float* WK    = (const float*)d_in[4];
    const float* WV    = (const float*)d_in[5];
    const float* WO    = (const float*)d_in[6];
    float* out = (float*)d_out;

    float* ws  = (float*)d_ws;
    float* Q   = ws;
    float* K   = ws + SEQ * DK;
    float* V   = ws + 2 * SEQ * DK;
    float* Wor = ws + 3 * SEQ * DK;     // 64 x 512

    void* args[] = { &xq, &xk, &amask, &WQ, &WK, &WV, &WO,
                     &Q, &K, &V, &Wor, &out };
    hipLaunchCooperativeKernel((void*)mha_fused, dim3(NB), dim3(NT),
                               args, 0, stream);
}

// Round 3
// 31.448 us; speedup vs baseline: 2.3407x; 2.3407x over previous
//
#include <hip/hip_runtime.h>
#include <math.h>

#define SEQ 512
#define DM  512
#define DK  64
#define NH  8
#define SCALE 0.125f   // 1/sqrt(64)

// ---------------------------------------------------------------------------
// Kernel 1: Q/K/V projections + reduced W_O.
// Blocks 0..511 (512 thr): row b -> Q[b,:], K[b,:], V[b,:].
//   Wave w handles d in [w*64,(w+1)*64). Lane l loads float4 of W at
//   row d = d0+(l>>4), cols (l&15)*4.. (fully coalesced 1KB per wave-load).
//   Partials for same k-quad live in lanes ^16/^32 -> 2 shfl_xor steps.
// Blocks 512..575: Wor[v,d] = sum_h WO[h*64+v, d]  (1 elem / thread).
// ---------------------------------------------------------------------------
__global__ __launch_bounds__(512) void qkv_wor_kernel(
    const float* __restrict__ xq, const float* __restrict__ xk,
    const float* __restrict__ WQ, const float* __restrict__ WK,
    const float* __restrict__ WV, const float* __restrict__ WO,
    float* __restrict__ Q, float* __restrict__ K,
    float* __restrict__ V, float* __restrict__ Wor)
{
    const int b   = blockIdx.x;
    const int tid = threadIdx.x;

    if (b >= SEQ) {                      // ---- Wor: 64 blocks x 512 thr ----
        const int e = (b - SEQ) * 512 + tid;   // flat v*512+d
        const int v = e >> 9, d = e & 511;
        float acc = 0.f;
        #pragma unroll
        for (int h = 0; h < NH; ++h) acc += WO[(h * DK + v) * DM + d];
        Wor[e] = acc;
        return;
    }

    __shared__ __align__(16) float xq_s[DM], xk_s[DM];
    __shared__ __align__(16) float part_s[3][8][DK];   // 6 KB

    {   // stage the two x rows (float4, coalesced)
        float4*       dq = reinterpret_cast<float4*>(xq_s);
        float4*       dk = reinterpret_cast<float4*>(xk_s);
        const float4* gq = reinterpret_cast<const float4*>(xq + b * DM);
        const float4* gk = reinterpret_cast<const float4*>(xk + b * DM);
        if      (tid < 128) dq[tid]       = gq[tid];
        else if (tid < 256) dk[tid - 128] = gk[tid - 128];
    }
    __syncthreads();

    const int w    = tid >> 6;           // wave 0..7 -> 64 d's each
    const int l    = tid & 63;
    const int dsub = l >> 4;             // 0..3
    const int kq   = (l & 15) * 4;       // k-quad base

    float4 aq = {0,0,0,0}, ak = {0,0,0,0}, av = {0,0,0,0};
    #pragma unroll
    for (int it = 0; it < 16; ++it) {
        const int d = w * 64 + it * 4 + dsub;
        const float4 wq = *reinterpret_cast<const float4*>(WQ + d * DK + kq);
        const float4 wk = *reinterpret_cast<const float4*>(WK + d * DK + kq);
        const float4 wv = *reinterpret_cast<const float4*>(WV + d * DK + kq);
        const float xqv = xq_s[d], xkv = xk_s[d];
        aq.x += xqv * wq.x; aq.y += xqv * wq.y; aq.z += xqv * wq.z; aq.w += xqv * wq.w;
        ak.x += xkv * wk.x; ak.y += xkv * wk.y; ak.z += xkv * wk.z; ak.w += xkv * wk.w;
        av.x += xkv * wv.x; av.y += xkv * wv.y; av.z += xkv * wv.z; av.w += xkv * wv.w;
    }
    // fold the 4 d-subgroups (lanes ^16, ^32)
    #pragma unroll
    for (int off = 16; off < 64; off <<= 1) {
        aq.x += __shfl_xor(aq.x, off, 64); aq.y += __shfl_xor(aq.y, off, 64);
        aq.z += __shfl_xor(aq.z, off, 64); aq.w += __shfl_xor(aq.w, off, 64);
        ak.x += __shfl_xor(ak.x, off, 64); ak.y += __shfl_xor(ak.y, off, 64);
        ak.z += __shfl_xor(ak.z, off, 64); ak.w += __shfl_xor(ak.w, off, 64);
        av.x += __shfl_xor(av.x, off, 64); av.y += __shfl_xor(av.y, off, 64);
        av.z += __shfl_xor(av.z, off, 64); av.w += __shfl_xor(av.w, off, 64);
    }
    if (dsub == 0) {
        *reinterpret_cast<float4*>(&part_s[0][w][kq]) = aq;
        *reinterpret_cast<float4*>(&part_s[1][w][kq]) = ak;
        *reinterpret_cast<float4*>(&part_s[2][w][kq]) = av;
    }
    __syncthreads();

    if (tid < 3 * DK) {                  // final cross-wave reduce
        const int m = tid >> 6, k = tid & 63;
        float s = 0.f;
        #pragma unroll
        for (int p = 0; p < 8; ++p) s += part_s[m][p][k];
        float* dst = (m == 0) ? Q : (m == 1) ? K : V;
        dst[b * DK + k] = s;
    }
}

// ---------------------------------------------------------------------------
// Kernel 2: per Q-row fused scores -> softmax -> PV -> (head @ Wor).
// One block (512 thr, 8 waves) per row. 1 score / thread, 1 output / thread.
// ---------------------------------------------------------------------------
__global__ __launch_bounds__(512) void attn_out_kernel(
    const float* __restrict__ Q, const float* __restrict__ K,
    const float* __restrict__ V, const float* __restrict__ Wor,
    const float* __restrict__ amask, float* __restrict__ out)
{
    const int s    = blockIdx.x;
    const int tid  = threadIdx.x;
    const int lane = tid & 63;
    const int w    = tid >> 6;

    __shared__ __align__(16) float q_s[DK];
    __shared__ float p_s[SEQ];
    __shared__ float red_s[8];
    __shared__ float hpart_s[8][DK];
    __shared__ float head_s[DK];

    if (tid < DK/4)
        reinterpret_cast<float4*>(q_s)[tid] =
            reinterpret_cast<const float4*>(Q + s * DK)[tid];
    const float am = amask[tid];
    __syncthreads();

    // ---- score t = tid ----
    float acc = 0.f;
    {
        const float4* k4 = reinterpret_cast<const float4*>(K + tid * DK);
        const float4* q4 = reinterpret_cast<const float4*>(q_s);
        #pragma unroll
        for (int d = 0; d < DK/4; ++d) {
            const float4 kv = k4[d], qv = q4[d];
            acc += qv.x*kv.x + qv.y*kv.y + qv.z*kv.z + qv.w*kv.w;
        }
        acc *= SCALE;
        if (am == 0.f) acc = -INFINITY;
    }

    // ---- block max ----
    float wm = acc;
    #pragma unroll
    for (int off = 32; off; off >>= 1) wm = fmaxf(wm, __shfl_xor(wm, off, 64));
    if (lane == 0) red_s[w] = wm;
    __syncthreads();
    float bmax = red_s[0];
    #pragma unroll
    for (int i = 1; i < 8; ++i) bmax = fmaxf(bmax, red_s[i]);
    __syncthreads();                       // red_s reused

    // ---- exp + block sum ----
    const float p = __expf(acc - bmax);
    p_s[tid] = p;
    float wsum = p;
    #pragma unroll
    for (int off = 32; off; off >>= 1) wsum += __shfl_xor(wsum, off, 64);
    if (lane == 0) red_s[w] = wsum;
    __syncthreads();
    float bsum = 0.f;
    #pragma unroll
    for (int i = 0; i < 8; ++i) bsum += red_s[i];
    const float inv = 1.f / bsum;

    // ---- PV: wave w covers t in [w*64, w*64+64) ----
    float hacc = 0.f;
    const int t0 = w * 64;
    #pragma unroll 4
    for (int t = t0; t < t0 + 64; ++t)
        hacc += p_s[t] * V[t * DK + lane];   // wave-coalesced 256B
    hpart_s[w][lane] = hacc;
    __syncthreads();
    if (tid < DK) {
        float hs = 0.f;
        #pragma unroll
        for (int p8 = 0; p8 < 8; ++p8) hs += hpart_s[p8][tid];
        head_s[tid] = hs * inv;
    }
    __syncthreads();

    // ---- out[s,d]: d = tid ----
    float o = 0.f;
    #pragma unroll 8
    for (int v = 0; v < DK; ++v)
        o += head_s[v] * Wor[v * DM + tid];  // coalesced across 512 thr
    out[s * DM + tid] = o;
}

extern "C" void kernel_launch(void* const* d_in, const int* in_sizes, int n_in,
                              void* d_out, int out_size, void* d_ws, size_t ws_size,
                              hipStream_t stream) {
    const float* xq    = (const float*)d_in[0];
    const float* xk    = (const float*)d_in[1];
    const float* amask = (const float*)d_in[2];
    const float* WQ    = (const float*)d_in[3];
    const float* WK    = (const float*)d_in[4];
    const float* WV    = (const float*)d_in[5];
    const float* WO    = (const float*)d_in[6];
    float* out = (float*)d_out;

    float* ws  = (float*)d_ws;
    float* Q   = ws;
    float* K   = ws + SEQ * DK;
    float* V   = ws + 2 * SEQ * DK;
    float* Wor = ws + 3 * SEQ * DK;     // 64 x 512

    qkv_wor_kernel<<<SEQ + DK, 512, 0, stream>>>(xq, xk, WQ, WK, WV, WO, Q, K, V, Wor);
    attn_out_kernel<<<SEQ, 512, 0, stream>>>(Q, K, V, Wor, amask, out);
}

// Round 4
// 22.095 us; speedup vs baseline: 3.3316x; 1.4233x over previous
//
#include <hip/hip_runtime.h>
#include <math.h>

#define SEQ 512
#define DM  512
#define DK  64
#define NH  8
#define SCALE 0.125f   // 1/sqrt(64)

// ---------------------------------------------------------------------------
// Kernel 1: Q/K/V projections (2 rows per block) + reduced W_O.
// Blocks 0..255 (512 thr): rows 2b,2b+1 -> Q/K/V. Wave w owns d-range
//   [w*64,(w+1)*64); lane l loads W float4 at row d0+(l>>4), cols (l&15)*4,
//   FMAs against BOTH x rows (register reuse), folds lanes ^16,^32.
// Blocks 256..319: Wor[v,d] = sum_h WO[h*64+v, d]  (1 elem / thread).
// ---------------------------------------------------------------------------
__global__ __launch_bounds__(512) void qkv_wor_kernel(
    const float* __restrict__ xq, const float* __restrict__ xk,
    const float* __restrict__ WQ, const float* __restrict__ WK,
    const float* __restrict__ WV, const float* __restrict__ WO,
    float* __restrict__ Q, float* __restrict__ K,
    float* __restrict__ V, float* __restrict__ Wor)
{
    const int b   = blockIdx.x;
    const int tid = threadIdx.x;

    if (b >= SEQ/2) {                    // ---- Wor: 64 blocks x 512 thr ----
        const int e = (b - SEQ/2) * 512 + tid;   // flat v*512+d
        const int v = e >> 9, d = e & 511;
        float acc = 0.f;
        #pragma unroll
        for (int h = 0; h < NH; ++h) acc += WO[(h * DK + v) * DM + d];
        Wor[e] = acc;
        return;
    }

    const int r0 = 2 * b;
    __shared__ __align__(16) float xq_s[2][DM], xk_s[2][DM];
    __shared__ __align__(16) float part_s[3][8][2][DK];   // 12 KB

    {   // stage 2 xq rows + 2 xk rows (contiguous float4 copy)
        if (tid < 256)
            reinterpret_cast<float4*>(xq_s)[tid] =
                reinterpret_cast<const float4*>(xq + r0 * DM)[tid];
        else
            reinterpret_cast<float4*>(xk_s)[tid - 256] =
                reinterpret_cast<const float4*>(xk + r0 * DM)[tid - 256];
    }
    __syncthreads();

    const int w    = tid >> 6;           // wave 0..7 -> 64 d's each
    const int l    = tid & 63;
    const int dsub = l >> 4;             // 0..3
    const int kq   = (l & 15) * 4;       // k-quad base

    float4 aq0{0,0,0,0}, aq1{0,0,0,0}, ak0{0,0,0,0},
           ak1{0,0,0,0}, av0{0,0,0,0}, av1{0,0,0,0};
    #pragma unroll
    for (int it = 0; it < 16; ++it) {
        const int d = w * 64 + it * 4 + dsub;
        const float4 wq = *reinterpret_cast<const float4*>(WQ + d * DK + kq);
        const float4 wk = *reinterpret_cast<const float4*>(WK + d * DK + kq);
        const float4 wv = *reinterpret_cast<const float4*>(WV + d * DK + kq);
        const float xq0 = xq_s[0][d], xq1 = xq_s[1][d];
        const float xk0 = xk_s[0][d], xk1 = xk_s[1][d];
        aq0.x += xq0*wq.x; aq0.y += xq0*wq.y; aq0.z += xq0*wq.z; aq0.w += xq0*wq.w;
        aq1.x += xq1*wq.x; aq1.y += xq1*wq.y; aq1.z += xq1*wq.z; aq1.w += xq1*wq.w;
        ak0.x += xk0*wk.x; ak0.y += xk0*wk.y; ak0.z += xk0*wk.z; ak0.w += xk0*wk.w;
        ak1.x += xk1*wk.x; ak1.y += xk1*wk.y; ak1.z += xk1*wk.z; ak1.w += xk1*wk.w;
        av0.x += xk0*wv.x; av0.y += xk0*wv.y; av0.z += xk0*wv.z; av0.w += xk0*wv.w;
        av1.x += xk1*wv.x; av1.y += xk1*wv.y; av1.z += xk1*wv.z; av1.w += xk1*wv.w;
    }
    #pragma unroll
    for (int off = 16; off < 64; off <<= 1) {
        aq0.x += __shfl_xor(aq0.x, off, 64); aq0.y += __shfl_xor(aq0.y, off, 64);
        aq0.z += __shfl_xor(aq0.z, off, 64); aq0.w += __shfl_xor(aq0.w, off, 64);
        aq1.x += __shfl_xor(aq1.x, off, 64); aq1.y += __shfl_xor(aq1.y, off, 64);
        aq1.z += __shfl_xor(aq1.z, off, 64); aq1.w += __shfl_xor(aq1.w, off, 64);
        ak0.x += __shfl_xor(ak0.x, off, 64); ak0.y += __shfl_xor(ak0.y, off, 64);
        ak0.z += __shfl_xor(ak0.z, off, 64); ak0.w += __shfl_xor(ak0.w, off, 64);
        ak1.x += __shfl_xor(ak1.x, off, 64); ak1.y += __shfl_xor(ak1.y, off, 64);
        ak1.z += __shfl_xor(ak1.z, off, 64); ak1.w += __shfl_xor(ak1.w, off, 64);
        av0.x += __shfl_xor(av0.x, off, 64); av0.y += __shfl_xor(av0.y, off, 64);
        av0.z += __shfl_xor(av0.z, off, 64); av0.w += __shfl_xor(av0.w, off, 64);
        av1.x += __shfl_xor(av1.x, off, 64); av1.y += __shfl_xor(av1.y, off, 64);
        av1.z += __shfl_xor(av1.z, off, 64); av1.w += __shfl_xor(av1.w, off, 64);
    }
    if (dsub == 0) {
        *reinterpret_cast<float4*>(&part_s[0][w][0][kq]) = aq0;
        *reinterpret_cast<float4*>(&part_s[0][w][1][kq]) = aq1;
        *reinterpret_cast<float4*>(&part_s[1][w][0][kq]) = ak0;
        *reinterpret_cast<float4*>(&part_s[1][w][1][kq]) = ak1;
        *reinterpret_cast<float4*>(&part_s[2][w][0][kq]) = av0;
        *reinterpret_cast<float4*>(&part_s[2][w][1][kq]) = av1;
    }
    __syncthreads();

    if (tid < 3 * 2 * DK) {              // 384 threads: cross-wave reduce
        const int m   = tid >> 7;        // 0:Q 1:K 2:V
        const int rem = tid & 127;
        const int r   = rem >> 6;
        const int k   = rem & 63;
        float s = 0.f;
        #pragma unroll
        for (int p = 0; p < 8; ++p) s += part_s[m][p][r][k];
        float* dst = (m == 0) ? Q : (m == 1) ? K : V;
        dst[(r0 + r) * DK + k] = s;
    }
}

// ---------------------------------------------------------------------------
// Kernel 2: 2 Q-rows per block (256 blocks x 512 thr). Every K/V/Wor load
// feeds both rows from registers.
// ---------------------------------------------------------------------------
__global__ __launch_bounds__(512) void attn_out_kernel(
    const float* __restrict__ Q, const float* __restrict__ K,
    const float* __restrict__ V, const float* __restrict__ Wor,
    const float* __restrict__ amask, float* __restrict__ out)
{
    const int r0   = 2 * blockIdx.x;
    const int tid  = threadIdx.x;
    const int lane = tid & 63;
    const int w    = tid >> 6;
    const int dsub = lane >> 4;
    const int kq   = (lane & 15) * 4;

    __shared__ __align__(16) float q_s[2][DK];
    __shared__ float p_s[2][SEQ];                 // 4 KB
    __shared__ float red_s[2][8];
    __shared__ __align__(16) float hpart_s[2][8][DK];   // 4 KB
    __shared__ __align__(16) float head_s[2][DK];
    __shared__ __align__(16) float4 epi_s[4][2][DM/4];  // 16 KB

    if (tid < 2 * DK / 4)                 // 2 contiguous Q rows, float4
        reinterpret_cast<float4*>(q_s)[tid] =
            reinterpret_cast<const float4*>(Q + r0 * DK)[tid];
    const float am = amask[tid];
    __syncthreads();

    // ---- scores for t = tid, both rows (K row reused) ----
    float sc0 = 0.f, sc1 = 0.f;
    {
        const float4* k4 = reinterpret_cast<const float4*>(K + tid * DK);
        const float4* qa = reinterpret_cast<const float4*>(q_s[0]);
        const float4* qb = reinterpret_cast<const float4*>(q_s[1]);
        #pragma unroll
        for (int d = 0; d < DK / 4; ++d) {
            const float4 kv = k4[d], q0 = qa[d], q1 = qb[d];
            sc0 += q0.x*kv.x + q0.y*kv.y + q0.z*kv.z + q0.w*kv.w;
            sc1 += q1.x*kv.x + q1.y*kv.y + q1.z*kv.z + q1.w*kv.w;
        }
        sc0 *= SCALE; sc1 *= SCALE;
        if (am == 0.f) { sc0 = -INFINITY; sc1 = -INFINITY; }
    }

    // ---- block max (both rows in parallel) ----
    float m0 = sc0, m1 = sc1;
    #pragma unroll
    for (int off = 32; off; off >>= 1) {
        m0 = fmaxf(m0, __shfl_xor(m0, off, 64));
        m1 = fmaxf(m1, __shfl_xor(m1, off, 64));
    }
    if (lane == 0) { red_s[0][w] = m0; red_s[1][w] = m1; }
    __syncthreads();
    float bmax0 = red_s[0][0], bmax1 = red_s[1][0];
    #pragma unroll
    for (int i = 1; i < 8; ++i) {
        bmax0 = fmaxf(bmax0, red_s[0][i]);
        bmax1 = fmaxf(bmax1, red_s[1][i]);
    }
    __syncthreads();                      // red_s reused

    // ---- exp + block sum ----
    const float p0 = __expf(sc0 - bmax0);
    const float p1 = __expf(sc1 - bmax1);
    p_s[0][tid] = p0;  p_s[1][tid] = p1;
    float s0 = p0, s1 = p1;
    #pragma unroll
    for (int off = 32; off; off >>= 1) {
        s0 += __shfl_xor(s0, off, 64);
        s1 += __shfl_xor(s1, off, 64);
    }
    if (lane == 0) { red_s[0][w] = s0; red_s[1][w] = s1; }
    __syncthreads();
    float bs0 = 0.f, bs1 = 0.f;
    #pragma unroll
    for (int i = 0; i < 8; ++i) { bs0 += red_s[0][i]; bs1 += red_s[1][i]; }
    const float inv0 = 1.f / bs0, inv1 = 1.f / bs1;

    // ---- PV: wave w covers t in [w*64,(w+1)*64); float4 over v-cols ----
    float4 h0{0,0,0,0}, h1{0,0,0,0};
    #pragma unroll
    for (int it = 0; it < 16; ++it) {
        const int t = w * 64 + it * 4 + dsub;
        const float4 v4 = *reinterpret_cast<const float4*>(V + t * DK + kq);
        const float pa = p_s[0][t], pb = p_s[1][t];
        h0.x += pa*v4.x; h0.y += pa*v4.y; h0.z += pa*v4.z; h0.w += pa*v4.w;
        h1.x += pb*v4.x; h1.y += pb*v4.y; h1.z += pb*v4.z; h1.w += pb*v4.w;
    }
    #pragma unroll
    for (int off = 16; off < 64; off <<= 1) {
        h0.x += __shfl_xor(h0.x, off, 64); h0.y += __shfl_xor(h0.y, off, 64);
        h0.z += __shfl_xor(h0.z, off, 64); h0.w += __shfl_xor(h0.w, off, 64);
        h1.x += __shfl_xor(h1.x, off, 64); h1.y += __shfl_xor(h1.y, off, 64);
        h1.z += __shfl_xor(h1.z, off, 64); h1.w += __shfl_xor(h1.w, off, 64);
    }
    if (dsub == 0) {
        *reinterpret_cast<float4*>(&hpart_s[0][w][kq]) = h0;
        *reinterpret_cast<float4*>(&hpart_s[1][w][kq]) = h1;
    }
    __syncthreads();
    if (tid < 2 * DK) {
        const int r = tid >> 6, k = tid & 63;
        float hs = 0.f;
        #pragma unroll
        for (int p = 0; p < 8; ++p) hs += hpart_s[r][p][k];
        head_s[r][k] = hs * (r == 0 ? inv0 : inv1);
    }
    __syncthreads();

    // ---- epilogue: out[r][d] = sum_v head[r][v]*Wor[v][d], float4 ----
    {
        const int dq = tid & 127;         // d-quad index
        const int vc = tid >> 7;          // v-chunk 0..3 (16 v each)
        float4 o0{0,0,0,0}, o1{0,0,0,0};
        #pragma unroll
        for (int j = 0; j < 16; ++j) {
            const int v = vc * 16 + j;
            const float4 wv = reinterpret_cast<const float4*>(Wor)[v * (DM/4) + dq];
            const float ha = head_s[0][v], hb = head_s[1][v];
            o0.x += ha*wv.x; o0.y += ha*wv.y; o0.z += ha*wv.z; o0.w += ha*wv.w;
            o1.x += hb*wv.x; o1.y += hb*wv.y; o1.z += hb*wv.z; o1.w += hb*wv.w;
        }
        epi_s[vc][0][dq] = o0;
        epi_s[vc][1][dq] = o1;
    }
    __syncthreads();
    if (tid < 256) {
        const int r = tid >> 7, dq = tid & 127;
        const float4 a = epi_s[0][r][dq], b2 = epi_s[1][r][dq];
        const float4 c = epi_s[2][r][dq], d2 = epi_s[3][r][dq];
        float4 s;
        s.x = a.x + b2.x + c.x + d2.x;
        s.y = a.y + b2.y + c.y + d2.y;
        s.z = a.z + b2.z + c.z + d2.z;
        s.w = a.w + b2.w + c.w + d2.w;
        reinterpret_cast<float4*>(out)[(r0 + r) * (DM/4) + dq] = s;
    }
}

extern "C" void kernel_launch(void* const* d_in, const int* in_sizes, int n_in,
                              void* d_out, int out_size, void* d_ws, size_t ws_size,
                              hipStream_t stream) {
    const float* xq    = (const float*)d_in[0];
    const float* xk    = (const float*)d_in[1];
    const float* amask = (const float*)d_in[2];
    const float* WQ    = (const float*)d_in[3];
    const float* WK    = (const float*)d_in[4];
    const float* WV    = (const float*)d_in[5];
    const float* WO    = (const float*)d_in[6];
    float* out = (float*)d_out;

    float* ws  = (float*)d_ws;
    float* Q   = ws;
    float* K   = ws + SEQ * DK;
    float* V   = ws + 2 * SEQ * DK;
    float* Wor = ws + 3 * SEQ * DK;     // 64 x 512

    qkv_wor_kernel<<<SEQ/2 + DK, 512, 0, stream>>>(xq, xk, WQ, WK, WV, WO, Q, K, V, Wor);
    attn_out_kernel<<<SEQ/2, 512, 0, stream>>>(Q, K, V, Wor, amask, out);
}